// Round 1
// baseline (231.012 us; speedup 1.0000x reference)
//
#include <hip/hip_runtime.h>
#include <hip/hip_bf16.h>
#include <cstdint>
#include <cstddef>

// Problem constants (fixed by the reference config)
#define BIMG   32
#define CIN_K  512
#define HH_    38
#define WW_    38
#define BHW    1444          // 38*38
#define NOUT   255           // NA*(NC+5)
#define MTOT   46208         // 32*1444, == 722*64 exactly

#define BM 64
#define BN 256
#define BK 32
#define KITERS (CIN_K / BK)  // 16
#define LDA 40               // 32 + 8 pad (bf16 elems) -> 80B row stride, 16B aligned
#define LDB 40

typedef __attribute__((ext_vector_type(8))) short  bf16x8;
typedef __attribute__((ext_vector_type(4))) float  floatx4;

static __device__ __forceinline__ unsigned f2bf(float f) {
    unsigned u = __builtin_bit_cast(unsigned, f);
    return (u + 0x7FFFu + ((u >> 16) & 1u)) >> 16;   // RNE to bf16, low 16 bits
}

__global__ __launch_bounds__(256, 2)
void yolo_head(const float* __restrict__ xin,   // [32,512,38,38]
               const float* __restrict__ cw,    // [255,512]
               const float* __restrict__ cb,    // [255]
               float* __restrict__ out)         // [32,38,38,3,85]
{
    __shared__ unsigned short As[BM * LDA];     //  5.0 KiB
    __shared__ unsigned short Bs[BN * LDB];     // 20.0 KiB

    const int t     = threadIdx.x;
    const int m_blk = blockIdx.x * BM;

    // ---- staging roles: waves 0,1 stage A; waves 2,3 stage B ----
    const float* pa = nullptr;
    int a_m2 = 0, a_c = 0, b_t2 = 0;
    if (t < 128) {
        a_m2 = (t & 31) * 2;          // m-pair within tile
        a_c  = (t >> 5) & 3;          // k-chunk of 8
        int mg   = m_blk + a_m2;
        int bi   = mg / BHW;          // image index (pair stays in one image: 1444 even)
        int r    = mg - bi * BHW;
        pa = xin + (size_t)bi * (CIN_K * BHW) + r;
    } else {
        b_t2 = t - 128;
    }

    floatx4 acc[4][4];
#pragma unroll
    for (int i = 0; i < 4; ++i)
#pragma unroll
        for (int j = 0; j < 4; ++j)
            acc[i][j] = (floatx4){0.f, 0.f, 0.f, 0.f};

    const int w    = t >> 6;      // wave id 0..3 -> n-slice
    const int lane = t & 63;
    const int l15  = lane & 15;
    const int q    = lane >> 4;   // quad 0..3 -> k-chunk for frags / m-subrow for C

#pragma unroll 1
    for (int it = 0; it < KITERS; ++it) {
        const int k0 = it * BK;
        __syncthreads();          // protect LDS from previous iter's readers

        if (t < 128) {
            // A tile: rows a_m2, a_m2+1; k = k0 + a_c*8 + [0..7]
            const float* p = pa + (size_t)(k0 + a_c * 8) * BHW;
            unsigned r0[4], r1[4];
#pragma unroll
            for (int u = 0; u < 4; ++u) {
                float2 e = *(const float2*)(p + (size_t)(2 * u)     * BHW); // k even
                float2 o = *(const float2*)(p + (size_t)(2 * u + 1) * BHW); // k odd
                r0[u] = f2bf(e.x) | (f2bf(o.x) << 16);   // row a_m2
                r1[u] = f2bf(e.y) | (f2bf(o.y) << 16);   // row a_m2+1
            }
            *(int4*)(&As[a_m2 * LDA + a_c * 8])       = *(int4*)r0;
            *(int4*)(&As[(a_m2 + 1) * LDA + a_c * 8]) = *(int4*)r1;
        } else {
            // B tile: 256 n-rows x 32 k; thread does 8 chunks of (1 n x 8 k)
#pragma unroll
            for (int s = 0; s < 8; ++s) {
                int n   = s * 32 + (b_t2 >> 2);
                int c   = b_t2 & 3;
                int ncl = n < NOUT ? n : NOUT - 1;     // clamp pad row 255
                const float* p = cw + (size_t)ncl * CIN_K + k0 + c * 8;
                float4 v0 = *(const float4*)(p);
                float4 v1 = *(const float4*)(p + 4);
                unsigned rr[4];
                rr[0] = f2bf(v0.x) | (f2bf(v0.y) << 16);
                rr[1] = f2bf(v0.z) | (f2bf(v0.w) << 16);
                rr[2] = f2bf(v1.x) | (f2bf(v1.y) << 16);
                rr[3] = f2bf(v1.z) | (f2bf(v1.w) << 16);
                *(int4*)(&Bs[n * LDB + c * 8]) = *(int4*)rr;
            }
        }

        __syncthreads();

        bf16x8 af[4], bf[4];
#pragma unroll
        for (int i = 0; i < 4; ++i) {
            int4 v = *(const int4*)(&As[(i * 16 + l15) * LDA + q * 8]);
            af[i] = __builtin_bit_cast(bf16x8, v);
        }
#pragma unroll
        for (int j = 0; j < 4; ++j) {
            int4 v = *(const int4*)(&Bs[(w * 64 + j * 16 + l15) * LDB + q * 8]);
            bf[j] = __builtin_bit_cast(bf16x8, v);
        }
#pragma unroll
        for (int i = 0; i < 4; ++i)
#pragma unroll
            for (int j = 0; j < 4; ++j)
                acc[i][j] = __builtin_amdgcn_mfma_f32_16x16x32_bf16(
                                af[i], bf[j], acc[i][j], 0, 0, 0);
    }

    // ---- fused YOLO decode epilogue ----
    // C/D layout (verified m89/m91): col(n) = lane&15, row(m) = quad*4 + reg
    int   moff[16];
    float fww[16], fhh[16];
#pragma unroll
    for (int i = 0; i < 4; ++i)
#pragma unroll
        for (int r = 0; r < 4; ++r) {
            int m   = m_blk + i * 16 + q * 4 + r;
            int rem = m % BHW;
            int hh  = rem / WW_;
            int ww2 = rem - hh * WW_;
            moff[i * 4 + r] = m * NOUT;
            fhh[i * 4 + r]  = (float)hh;
            fww[i * 4 + r]  = (float)ww2;
        }

#pragma unroll
    for (int j = 0; j < 4; ++j) {
        int  n     = w * 64 + j * 16 + l15;
        bool valid = n < NOUT;
        int  ncl   = valid ? n : NOUT - 1;
        int  ai    = ncl / 85;
        int  ji    = ncl - ai * 85;        // class within anchor (lane-constant per j)
        float bias = cb[ncl];
        float aw   = (ai == 0) ? 30.f : (ai == 1) ? 62.f : 59.f;
        float ah   = (ai == 0) ? 61.f : (ai == 1) ? 45.f : 119.f;

        if (ji < 2) {                       // bx / by: (sigmoid + grid_off) * 16
#pragma unroll
            for (int i = 0; i < 4; ++i)
#pragma unroll
                for (int r = 0; r < 4; ++r) {
                    float v  = acc[i][j][r] + bias;
                    float sg = 1.f / (1.f + __expf(-v));
                    float of = (ji == 0) ? fww[i * 4 + r] : fhh[i * 4 + r];
                    if (valid) out[moff[i * 4 + r] + n] = (sg + of) * 16.f;
                }
        } else if (ji < 4) {                // bw / bh: exp * anchor
            float sc = (ji == 2) ? aw : ah;
#pragma unroll
            for (int i = 0; i < 4; ++i)
#pragma unroll
                for (int r = 0; r < 4; ++r) {
                    float v = acc[i][j][r] + bias;
                    if (valid) out[moff[i * 4 + r] + n] = __expf(v) * sc;
                }
        } else {                            // raw objectness / class logits
#pragma unroll
            for (int i = 0; i < 4; ++i)
#pragma unroll
                for (int r = 0; r < 4; ++r) {
                    float v = acc[i][j][r] + bias;
                    if (valid) out[moff[i * 4 + r] + n] = v;
                }
        }
    }
}

extern "C" void kernel_launch(void* const* d_in, const int* in_sizes, int n_in,
                              void* d_out, int out_size, void* d_ws, size_t ws_size,
                              hipStream_t stream) {
    const float* xin = (const float*)d_in[0];
    const float* cw  = (const float*)d_in[1];
    const float* cb  = (const float*)d_in[2];
    float*       out = (float*)d_out;

    dim3 grid(MTOT / BM);   // 722
    dim3 block(256);
    hipLaunchKernelGGL(yolo_head, grid, block, 0, stream, xin, cw, cb, out);
}